// Round 2
// baseline (455.521 us; speedup 1.0000x reference)
//
#include <hip/hip_runtime.h>
#include <hip/hip_bf16.h>
#include <stdint.h>
#include <stddef.h>

typedef __bf16 bf16_t;
typedef __attribute__((ext_vector_type(8))) __bf16 bf16x8;
typedef __attribute__((ext_vector_type(4))) __bf16 bf16x4;
typedef __attribute__((ext_vector_type(4))) float f32x4;
typedef __attribute__((ext_vector_type(4))) int i32x4;

#define M_DIM 32768
#define N_DIM 4096
#define K_DIM 1024

static __device__ __forceinline__ void gload16(const void* g, void* s) {
  // async global->LDS, 16B per lane; LDS dest is wave-uniform base + lane*16
  __builtin_amdgcn_global_load_lds(
      (const __attribute__((address_space(1))) void*)g,
      (__attribute__((address_space(3))) void*)s,
      16, 0, 0);
}

// ---------------- x: fp32 [M][K] -> bf16 [M][K] ----------------
__global__ void cvt_x_kernel(const float* __restrict__ x, bf16_t* __restrict__ xb) {
  const long n8 = (long)M_DIM * K_DIM / 8;
  long i = (long)blockIdx.x * blockDim.x + threadIdx.x;
  const long stride = (long)gridDim.x * blockDim.x;
  for (; i < n8; i += stride) {
    const float4* p = (const float4*)(x + i * 8);
    float4 v0 = p[0];
    float4 v1 = p[1];
    bf16x8 o;
    o[0] = (__bf16)v0.x; o[1] = (__bf16)v0.y; o[2] = (__bf16)v0.z; o[3] = (__bf16)v0.w;
    o[4] = (__bf16)v1.x; o[5] = (__bf16)v1.y; o[6] = (__bf16)v1.z; o[7] = (__bf16)v1.w;
    *(bf16x8*)(xb + i * 8) = o;
  }
}

// ---------------- w: int32 [K][N] -> bf16 Wt [N][K] (exact) ----------------
// NOTE: harness pushes integer inputs as int32, values in [-127,127] (exact in bf16)
__global__ void cvt_w_kernel(const int* __restrict__ qw, bf16_t* __restrict__ wt) {
  __shared__ bf16_t t[64][72];  // [n_local][k_local], padded (+8 breaks bank aliasing)
  const int bk = blockIdx.x & 15;   // K/64 = 16
  const int bn = blockIdx.x >> 4;   // N/64 = 64
  const int k0 = bk * 64, n0 = bn * 64;
  const int tid = threadIdx.x;
  {
    const int kl = tid >> 2;           // 0..63: row of qw tile
    const int nc = (tid & 3) * 16;     // 16-int chunk along n
    const int* src = qw + (long)(k0 + kl) * N_DIM + n0 + nc;
#pragma unroll
    for (int c = 0; c < 4; ++c) {
      i32x4 v = *(const i32x4*)(src + c * 4);
#pragma unroll
      for (int j = 0; j < 4; ++j)
        t[nc + c * 4 + j][kl] = (bf16_t)(float)v[j];
    }
  }
  __syncthreads();
  {
    const int nl = tid >> 2;           // 0..63: row of Wt tile
    const int kc = (tid & 3) * 16;     // 16 elems along k
    bf16_t* dst = wt + (long)(n0 + nl) * K_DIM + k0 + kc;
#pragma unroll
    for (int j = 0; j < 16; ++j) dst[j] = t[nl][kc + j];
  }
}

// ---------------- GEMM: C = (A @ Bt^T) * scale + bias ----------------
// A: bf16 [M][K] (APRE) or fp32 [M][K] converted on the fly
// Bt: bf16 [N][K]
// 128x128 tile, BK=64, 4 waves (2x2), per-wave 64x64 = 4x4 frags of 16x16x32
template <bool APRE>
__global__ __launch_bounds__(256, 2) void gemm_kernel(
    const bf16_t* __restrict__ A, const float* __restrict__ Af,
    const bf16_t* __restrict__ Bt, const float* __restrict__ scale_p,
    const float* __restrict__ bias, float* __restrict__ C) {
  __shared__ bf16_t lA[128][64];  // 16 KB
  __shared__ bf16_t lB[128][64];  // 16 KB

  // XCD-bijective swizzle (nwg = 8192, divisible by 8): consecutive wg on one
  // XCD walk tm within a shared tn (B-panel stays in that XCD's L2)
  const int nwg = gridDim.x;
  int wg = blockIdx.x;
  wg = (wg & 7) * (nwg >> 3) + (wg >> 3);
  const int tm = wg & 255;   // M/128 = 256
  const int tn = wg >> 8;    // N/128 = 32

  const int tid = threadIdx.x;
  const int wave = tid >> 6;
  const int lane = tid & 63;
  const int lr = lane & 15;   // frag row (A) / col (B,C)
  const int lg = lane >> 4;   // k-octet group; C row group
  const int wm = wave >> 1;
  const int wn = wave & 1;

  const long aRow0 = (long)tm * 128;
  const long bRow0 = (long)tn * 128;

  // gload staging: issue i covers LDS bytes [i*4096 + t*16): row = i*32 + t/8, col = (t&7)*8
  const bf16_t* aSrc = A + (aRow0 + (tid >> 3)) * K_DIM + (tid & 7) * 8;
  const bf16_t* bSrc = Bt + (bRow0 + (tid >> 3)) * K_DIM + (tid & 7) * 8;
  char* ldsA = (char*)&lA[0][0] + wave * 1024;  // wave-uniform dest
  char* ldsB = (char*)&lB[0][0] + wave * 1024;

  f32x4 acc[4][4] = {};

  for (int k0 = 0; k0 < K_DIM; k0 += 64) {
    __syncthreads();  // previous compute done reading LDS
    if (APRE) {
#pragma unroll
      for (int i = 0; i < 4; ++i)
        gload16(aSrc + (long)i * 32 * K_DIM + k0, ldsA + i * 4096);
    } else {
      // reg-stage A: fp32 load + cvt -> ds_write_b64; flat elem e = j*1024 + tid*4
#pragma unroll
      for (int j = 0; j < 8; ++j) {
        const int e = j * 1024 + tid * 4;
        const int row = e >> 6;
        const int col = e & 63;
        float4 v = *(const float4*)(Af + (aRow0 + row) * K_DIM + k0 + col);
        bf16x4 o;
        o[0] = (__bf16)v.x; o[1] = (__bf16)v.y; o[2] = (__bf16)v.z; o[3] = (__bf16)v.w;
        *(bf16x4*)((char*)&lA[0][0] + (size_t)e * 2) = o;
      }
    }
#pragma unroll
    for (int i = 0; i < 4; ++i)
      gload16(bSrc + (long)i * 32 * K_DIM + k0, ldsB + i * 4096);
    __syncthreads();  // compiler drains vmcnt+lgkm before barrier

#pragma unroll
    for (int kk = 0; kk < 2; ++kk) {
      bf16x8 af[4], bg[4];
#pragma unroll
      for (int m = 0; m < 4; ++m)
        af[m] = *(const bf16x8*)&lA[wm * 64 + m * 16 + lr][kk * 32 + lg * 8];
#pragma unroll
      for (int n = 0; n < 4; ++n)
        bg[n] = *(const bf16x8*)&lB[wn * 64 + n * 16 + lr][kk * 32 + lg * 8];
#pragma unroll
      for (int m = 0; m < 4; ++m)
#pragma unroll
        for (int n = 0; n < 4; ++n)
          acc[m][n] = __builtin_amdgcn_mfma_f32_16x16x32_bf16(af[m], bg[n], acc[m][n], 0, 0, 0);
    }
  }

  // epilogue: out = acc * scale + bias[col]
  // C/D layout (m89-verified): col = lane&15, row = (lane>>4)*4 + reg
  const float s = *scale_p;
  const int col0 = (tn << 7) + wn * 64;
  const int row0 = (tm << 7) + wm * 64 + lg * 4;
#pragma unroll
  for (int n = 0; n < 4; ++n) {
    const int col = col0 + n * 16 + lr;
    const float bv = bias[col];
#pragma unroll
    for (int m = 0; m < 4; ++m) {
      float* cp = C + (long)(row0 + m * 16) * N_DIM + col;
#pragma unroll
      for (int j = 0; j < 4; ++j)
        cp[(long)j * N_DIM] = acc[m][n][j] * s + bv;
    }
  }
}

extern "C" void kernel_launch(void* const* d_in, const int* in_sizes, int n_in,
                              void* d_out, int out_size, void* d_ws, size_t ws_size,
                              hipStream_t stream) {
  const float* x = (const float*)d_in[0];
  const int* qw = (const int*)d_in[1];       // int32! harness pushes ints as int32
  const float* scale = (const float*)d_in[2];
  const float* bias = (const float*)d_in[3];
  float* out = (float*)d_out;

  const size_t wt_bytes = (size_t)N_DIM * K_DIM * 2;  // 8 MB
  const size_t xb_bytes = (size_t)M_DIM * K_DIM * 2;  // 64 MB
  bf16_t* wt = (bf16_t*)d_ws;
  bf16_t* xb = (bf16_t*)((char*)d_ws + wt_bytes);
  const bool apre = ws_size >= wt_bytes + xb_bytes;

  // w -> Wt bf16 [N][K] (exact int8-range -> bf16)
  cvt_w_kernel<<<dim3((K_DIM / 64) * (N_DIM / 64)), dim3(256), 0, stream>>>(qw, wt);

  if (apre) {
    cvt_x_kernel<<<dim3(2048), dim3(256), 0, stream>>>(x, xb);
    gemm_kernel<true><<<dim3((M_DIM / 128) * (N_DIM / 128)), dim3(256), 0, stream>>>(
        xb, nullptr, wt, scale, bias, out);
  } else {
    gemm_kernel<false><<<dim3((M_DIM / 128) * (N_DIM / 128)), dim3(256), 0, stream>>>(
        nullptr, x, wt, scale, bias, out);
  }
}